// Round 5
// baseline (1009.988 us; speedup 1.0000x reference)
//
#include <hip/hip_runtime.h>

typedef unsigned short ushort_t;
typedef __attribute__((ext_vector_type(4))) unsigned short bfx4;
typedef __attribute__((ext_vector_type(8))) unsigned short bfx8;
typedef __attribute__((ext_vector_type(8))) short sfx8;
typedef __attribute__((ext_vector_type(4))) float fx4;

__device__ __forceinline__ float bf2f(unsigned short u){
  unsigned int x = ((unsigned int)u) << 16;
  float f; __builtin_memcpy(&f, &x, 4); return f;
}
__device__ __forceinline__ unsigned short f2bf(float f){
  unsigned int x; __builtin_memcpy(&x, &f, 4);
  x += 0x7fffu + ((x >> 16) & 1u);
  return (unsigned short)(x >> 16);
}

// ---------------- one-off: pack W_so into bf16 MFMA-B-fragment order
__global__ void k_pack(const float* __restrict__ wso, ushort_t* __restrict__ wpk)
{
  int idx = blockIdx.x * 256 + threadIdx.x;
  if (idx >= 8*5*64*8) return;
  int j    = idx & 7;
  int lane = (idx >> 3) & 63;
  int ks   = (idx >> 9) % 5;
  int nt   = idx / 2560;
  int mrow = lane & 15, quad = lane >> 4;
  int o = nt*16 + mrow;
  int k = ks*32 + quad*8 + j;
  float v = (k < 153) ? wso[o*153 + k] : 0.f;
  wpk[idx] = f2bf(v);
}

// ---------------- Edge scatter: factorized Fsum/cnt histogram, direct global atomics.
// P privatized copies (P power of 2); copy = blockIdx & (P-1) aligns copies with the
// XCD round-robin block dispatch -> atomics mostly stay in the local L2 slice.
__global__ __launch_bounds__(256) void k_scatter(const int* __restrict__ ei,
                                                 const float* __restrict__ frames,
                                                 float* __restrict__ sumsp,
                                                 int E, int N, int Pm1)
{
  const int tid  = threadIdx.x;
  const int blk  = blockIdx.x;
  float* sp0 = sumsp + (size_t)(blk & Pm1) * ((size_t)N * 10);
  const int base = blk * 1024;          // 4 edges per thread, coalesced per sub-iter

  int   row[4];
  float F[4][9];
  #pragma unroll
  for (int u = 0; u < 4; u++){
    int e = base + u*256 + tid;
    row[u] = -1;
    if (e < E){
      row[u] = ei[e];
      __builtin_memcpy(F[u], frames + (size_t)e * 9, 36);   // coalesced (stride-36 lanes)
    }
  }
  #pragma unroll
  for (int u = 0; u < 4; u++){
    if (row[u] >= 0){
      float* sp = sp0 + (size_t)row[u] * 10;
      #pragma unroll
      for (int t = 0; t < 9; t++) atomicAdd(&sp[t], F[u][t]); // fire-and-forget
      atomicAdd(&sp[9], 1.0f);
    }
  }
}

// ---------------- Kernel C: node main pass (vh, vdf, vnorm, Fsum->sh, MFMA s, silu, gate, vrep)
#define NPB 64
#define MS  168   // padded row stride (elements); 168*2B/4 = 84 ≡ 20 mod 32 -> <=2-way LDS conflicts
#define WGS 136   // sm_wg row stride (shorts): 272B, 16B-aligned, 68 dw ≡ 4 mod 32 -> <=2-way

__global__ __launch_bounds__(256) void k_node(
    const float* __restrict__ scalar, const float* __restrict__ vec,
    const float* __restrict__ sumsp,
    const float* __restrict__ wdown, const float* __restrict__ wdf,
    const ushort_t* __restrict__ wpk, const float* __restrict__ bso,
    const float* __restrict__ wup,   const float* __restrict__ wg,
    const float* __restrict__ bg,
    float* __restrict__ out0, float* __restrict__ out1, int N, int P)
{
  __shared__ __align__(16) ushort_t sm_merged[NPB * MS];  // phases 0-1: first 12288B hold vec f32
  __shared__ __align__(16) ushort_t sm_vh[NPB * 48];
  __shared__ __align__(16) ushort_t sm_wg[16 * WGS];
  __shared__ float  sm_sh[NPB * 10];     // Fsum[9] + cnt per node
  __shared__ float  sm_vdf[NPB * 9];     // vdf[d*3+c] per node
  __shared__ float  sm_wup[256];
  __shared__ float  sm_wd[256];          // transposed: sm_wd[k*16+h] = wdown[h*16+k]
  __shared__ float  sm_wdf[48];
  __shared__ float  sm_bso[128];
  __shared__ float  sm_bg[16];

  const int tid = threadIdx.x;
  const int n0  = blockIdx.x * NPB;

  // ---- phase 0: stage vec (as f32 into sm_merged), wd/wdf, reduce P privatized Fsum copies
  {
    int nv = N - n0; if (nv > NPB) nv = NPB;
    const int valid = nv * 48;
    fx4* scratch = (fx4*)sm_merged;
    for (int idx = tid; idx < NPB*48/4; idx += 256){
      fx4 val = {0.f, 0.f, 0.f, 0.f};
      if (idx*4 < valid) val = *(const fx4*)(vec + (size_t)n0*48 + idx*4);
      scratch[idx] = val;
    }
  }
  sm_wd[tid] = wdown[(tid & 15)*16 + (tid >> 4)];   // transpose on load
  if (tid < 48) sm_wdf[tid] = wdf[tid];
  {
    const size_t stride = (size_t)N * 10;
    for (int idx = tid; idx < NPB*10; idx += 256){
      int ni = idx / 10, sl = idx - ni*10;
      int g = n0 + ni;
      float acc = 0.f;
      if (g < N){
        const float* pb = sumsp + (size_t)g*10 + sl;
        for (int p = 0; p < P; p++) acc += pb[(size_t)p * stride];
      }
      sm_sh[idx] = acc;
    }
  }
  __syncthreads();

  // ---- phase 1: vh (1024 items (ni,h), weight reads broadcast) + vdf (192 items)
  #pragma unroll
  for (int it = 0; it < 4; it++){
    int idx = tid + it*256;
    int ni = idx >> 4, h = idx & 15;
    const float* sv = (const float*)sm_merged + ni*48;
    float a0 = 0.f, a1 = 0.f, a2 = 0.f;
    #pragma unroll
    for (int k = 0; k < 16; k++){
      float w = sm_wd[k*16 + h];
      a0 += sv[k*3+0]*w; a1 += sv[k*3+1]*w; a2 += sv[k*3+2]*w;
    }
    sm_vh[ni*48 +  0 + h] = f2bf(a0);
    sm_vh[ni*48 + 16 + h] = f2bf(a1);
    sm_vh[ni*48 + 32 + h] = f2bf(a2);
  }
  if (tid < NPB*3){
    const int ni = tid / 3, d = tid - ni*3;
    const float* sv = (const float*)sm_merged + ni*48;
    float c0 = 0.f, c1 = 0.f, c2 = 0.f;
    #pragma unroll
    for (int k = 0; k < 16; k++){
      float v = sv[k*3 + d];
      c0 += v * sm_wdf[ 0 + k];
      c1 += v * sm_wdf[16 + k];
      c2 += v * sm_wdf[32 + k];
    }
    sm_vdf[ni*9 + d*3 + 0] = c0;
    sm_vdf[ni*9 + d*3 + 1] = c1;
    sm_vdf[ni*9 + d*3 + 2] = c2;
  }
  __syncthreads();

  // ---- phase 2: assemble merged row (scalar | vnorm | sh | pad), stage small tensors
  for (int idx = tid; idx < NPB*32; idx += 256){
    int ni = idx >> 5, c4 = (idx & 31) * 4;
    int g = n0 + ni;
    if (g < N){
      fx4 x = *(const fx4*)(scalar + (size_t)g*128 + c4);
      bfx4 b; b[0]=f2bf(x[0]); b[1]=f2bf(x[1]); b[2]=f2bf(x[2]); b[3]=f2bf(x[3]);
      *(bfx4*)(sm_merged + ni*MS + c4) = b;
    } else {
      bfx4 b = {0,0,0,0};
      *(bfx4*)(sm_merged + ni*MS + c4) = b;
    }
  }
  #pragma unroll
  for (int it = 0; it < 4; it++){
    int idx = tid + it*256;
    int ni = idx >> 4, h = idx & 15;
    float x0 = bf2f(sm_vh[ni*48 +  0 + h]);
    float x1 = bf2f(sm_vh[ni*48 + 16 + h]);
    float x2 = bf2f(sm_vh[ni*48 + 32 + h]);
    sm_merged[ni*MS + 128 + h] = f2bf(sqrtf(x0*x0 + x1*x1 + x2*x2 + 1e-8f));
  }
  // sh[c*3+i] = (Fsum[i][:] . vdf[:][c]) / max(cnt,1)   (factorized rotation, per node)
  for (int idx = tid; idx < NPB*9; idx += 256){
    int ni = idx / 9, t = idx - ni*9;
    int c = t / 3, i3 = (t - c*3) * 3;
    float cnt = sm_sh[ni*10 + 9];
    float inv = 1.0f / fmaxf(cnt, 1.0f);
    const float* Fs = sm_sh + ni*10;
    const float* vd = sm_vdf + ni*9;
    float val = Fs[i3+0]*vd[0*3+c] + Fs[i3+1]*vd[1*3+c] + Fs[i3+2]*vd[2*3+c];
    sm_merged[ni*MS + 144 + t] = f2bf(val * inv);
  }
  for (int idx = tid; idx < NPB*7; idx += 256){
    int ni = idx / 7, t = idx - ni*7;
    sm_merged[ni*MS + 153 + t] = 0;            // zero MFMA pad cols 153..159
  }
  for (int idx = tid; idx < 2048; idx += 256)
    sm_wg[(idx >> 7)*WGS + (idx & 127)] = f2bf(wg[idx]);
  sm_wup[tid] = wup[tid];
  if (tid < 128) sm_bso[tid] = bso[tid];
  if (tid < 16) sm_bg[tid] = bg[tid];
  __syncthreads();

  // ---- phase 3: MFMA (B-fragments streamed from prepacked global, L2-resident)
  const int lane = tid & 63;
  const int wv   = tid >> 6;
  const int mrow = lane & 15;
  const int quad = lane >> 4;
  sfx8 afr[5];
  {
    const ushort_t* ab = sm_merged + (wv*16 + mrow)*MS + quad*8;
    #pragma unroll
    for (int ks = 0; ks < 5; ks++) afr[ks] = *(const sfx8*)(ab + ks*32);
  }
  const ushort_t* wb = wpk + lane*8;
  #pragma unroll
  for (int nt = 0; nt < 8; nt++){
    fx4 acc = {0.f, 0.f, 0.f, 0.f};
    #pragma unroll
    for (int ks = 0; ks < 5; ks++){
      sfx8 bfr = *(const sfx8*)(wb + (size_t)(nt*5 + ks)*64*8);
      acc = __builtin_amdgcn_mfma_f32_16x16x32_bf16(afr[ks], bfr, acc, 0, 0, 0);
    }
    const int o = nt*16 + mrow;
    const float bso_v = sm_bso[o];
    #pragma unroll
    for (int r = 0; r < 4; r++){
      int m = quad*4 + r;
      int g = n0 + wv*16 + m;
      float s = acc[r] + bso_v;
      float sact = s / (1.f + __expf(-s));
      if (g < N) out0[(size_t)g*128 + o] = sact;
      sm_merged[(wv*16 + m)*MS + o] = f2bf(sact);
    }
  }
  __syncthreads();

  // ---- phase 4: gate + vrep
  for (int it = 0; it < 4; it++){
    int widx = tid + it*256;
    int ni = widx >> 4, o16 = widx & 15;
    int g = n0 + ni;
    float acc = sm_bg[o16];
    #pragma unroll
    for (int j8 = 0; j8 < 16; j8++){
      bfx8 svv = *(const bfx8*)(sm_merged + ni*MS + j8*8);
      bfx8 wv8 = *(const bfx8*)(sm_wg + o16*WGS + j8*8);
      #pragma unroll
      for (int t = 0; t < 8; t++) acc += bf2f(svv[t]) * bf2f(wv8[t]);
    }
    float sig = 1.f / (1.f + __expf(-acc));
    #pragma unroll
    for (int d = 0; d < 3; d++){
      float r = 0.f;
      #pragma unroll
      for (int h = 0; h < 16; h++)
        r += bf2f(sm_vh[ni*48 + d*16 + h]) * sm_wup[o16*16 + h];
      if (g < N) out1[((size_t)g*16 + o16)*3 + d] = r * sig;
    }
  }
}

extern "C" void kernel_launch(void* const* d_in, const int* in_sizes, int n_in,
                              void* d_out, int out_size, void* d_ws, size_t ws_size,
                              hipStream_t stream)
{
  const float* scalar = (const float*)d_in[0];
  const float* vec    = (const float*)d_in[1];
  const int*   ei     = (const int*)d_in[2];
  const float* frames = (const float*)d_in[3];
  const float* wdown  = (const float*)d_in[4];
  const float* wdf    = (const float*)d_in[5];
  const float* wso    = (const float*)d_in[6];
  const float* bso    = (const float*)d_in[7];
  const float* wup    = (const float*)d_in[8];
  const float* wg     = (const float*)d_in[9];
  const float* bg     = (const float*)d_in[10];

  const int N = in_sizes[0] / 128;
  const int E = in_sizes[2] / 2;

  char* wp = (char*)d_ws;
  ushort_t* wpk   = (ushort_t*)wp;                 wp += (size_t)8*5*64*8 * sizeof(ushort_t);
  float*    sumsp = (float*)wp;

  const size_t copyB = (size_t)N * 10 * sizeof(float);
  const size_t headB = (size_t)(wp - (char*)d_ws);
  int P = 8;                                       // privatized copies, power of 2
  while (P > 1 && headB + (size_t)P * copyB > ws_size) P >>= 1;

  float* out0 = (float*)d_out;                    // silu(s): N x 128 f32
  float* out1 = out0 + (size_t)N * 128;           // vrep:    N x 16 x 3 f32

  (void)hipMemsetAsync(sumsp, 0, (size_t)P * copyB, stream);
  k_pack<<<(8*5*64*8 + 255)/256, 256, 0, stream>>>(wso, wpk);
  k_scatter<<<(E + 1023) / 1024, 256, 0, stream>>>(ei, frames, sumsp, E, N, P - 1);
  k_node<<<(N + NPB - 1) / NPB, 256, 0, stream>>>(scalar, vec, sumsp,
                                                  wdown, wdf, wpk, bso, wup, wg, bg,
                                                  out0, out1, N, P);
}

// Round 6
// 343.564 us; speedup vs baseline: 2.9397x; 2.9397x over previous
//
#include <hip/hip_runtime.h>

typedef unsigned short ushort_t;
typedef __attribute__((ext_vector_type(4))) unsigned short bfx4;
typedef __attribute__((ext_vector_type(8))) unsigned short bfx8;
typedef __attribute__((ext_vector_type(8))) short sfx8;
typedef __attribute__((ext_vector_type(4))) float fx4;

#define NABLK  256     // phase-A blocks
#define RTH    1024    // phase-A threads per block
#define KBMAX  52      // max buckets (node>>10); N <= 53248 else fallback
#define CAPL   48      // LDS records per bucket (phase A)
#define FLC    16      // flush chunk, records (16*48B = 768B, line-aligned)
#define RSZ    12      // record dwords (48 B): [0]=loc, [1..9]=F, [10..11]=pad
#define SPLITN 8       // phase-B sub-blocks per bucket
#define QMAX   160     // flush queue capacity per round (<= KBMAX*3)

__device__ __forceinline__ float bf2f(unsigned short u){
  unsigned int x = ((unsigned int)u) << 16;
  float f; __builtin_memcpy(&f, &x, 4); return f;
}
__device__ __forceinline__ unsigned short f2bf(float f){
  unsigned int x; __builtin_memcpy(&x, &f, 4);
  x += 0x7fffu + ((x >> 16) & 1u);
  return (unsigned short)(x >> 16);
}

// ---------------- one-off: pack W_so into bf16 MFMA-B-fragment order
__global__ void k_pack(const float* __restrict__ wso, ushort_t* __restrict__ wpk)
{
  int idx = blockIdx.x * 256 + threadIdx.x;
  if (idx >= 8*5*64*8) return;
  int j    = idx & 7;
  int lane = (idx >> 3) & 63;
  int ks   = (idx >> 9) % 5;
  int nt   = idx / 2560;
  int mrow = lane & 15, quad = lane >> 4;
  int o = nt*16 + mrow;
  int k = ks*32 + quad*8 + j;
  float v = (k < 153) ? wso[o*153 + k] : 0.f;
  wpk[idx] = f2bf(v);
}

// ---------------- pure-atomic fallback (ws too small / N too large)
__global__ void k_edge(const int* __restrict__ ei, const float* __restrict__ frames,
                       float* __restrict__ sums, int E)
{
  int e = blockIdx.x * 256 + threadIdx.x;
  if (e >= E) return;
  int row = ei[e];
  const float* fp = frames + (size_t)e * 9;
  float F[9];
  __builtin_memcpy(F, fp, 36);
  float* sp = sums + (size_t)row * 10;
  #pragma unroll
  for (int t = 0; t < 9; t++) atomicAdd(&sp[t], F[t]);
  atomicAdd(&sp[9], 1.0f);
}

// ---------------- Phase A: LDS-staged radix partition into per-(bucket,block) record streams.
// All record traffic is full-line coalesced (768B aligned chunks). No global atomics except
// statistically-rare overflow fallback into sums.
__global__ __launch_bounds__(RTH) void k_part(const int* __restrict__ ei,
                                              const float* __restrict__ frames,
                                              float* __restrict__ recs,
                                              int* __restrict__ counts,
                                              float* __restrict__ sums,
                                              int E, int EPB, int KB, int CAPG)
{
  __shared__ float s_buf[KBMAX * CAPL * RSZ];   // ~119KB (>64KB static OK on gfx950)
  __shared__ int   s_cnt[KBMAX];
  __shared__ int   s_gof[KBMAX];
  __shared__ int   s_qb[QMAX];                  // (bucket<<8) | srcStartSlot
  __shared__ int   s_qd[QMAX];                  // dst record offset, or -1 = fallback
  __shared__ int   s_nq;

  const int tid  = threadIdx.x;
  const int ablk = blockIdx.x;
  const int e0 = ablk * EPB;
  const int e1 = min(e0 + EPB, E);

  for (int b = tid; b < KB; b += RTH){ s_cnt[b] = 0; s_gof[b] = 0; }
  if (tid == 0) s_nq = 0;
  __syncthreads();

  for (int i0 = e0; i0 < e1; i0 += RTH){
    // ---- classify (coalesced reads of ei + frames)
    int e = i0 + tid;
    if (e < e1){
      int row = ei[e];
      float F[9];
      __builtin_memcpy(F, frames + (size_t)e * 9, 36);
      int b   = row >> 10;
      int loc = row & 1023;
      int slot = atomicAdd(&s_cnt[b], 1);
      if (slot < CAPL){
        float lf; __builtin_memcpy(&lf, &loc, 4);
        fx4* dst = (fx4*)(s_buf + (b * CAPL + slot) * RSZ);
        fx4 a = {lf, F[0], F[1], F[2]};
        fx4 c = {F[3], F[4], F[5], F[6]};
        fx4 d = {F[7], F[8], 0.f, 0.f};
        dst[0] = a; dst[1] = c; dst[2] = d;
      } else {
        // LDS buffer overflow (P ~ 1e-5): fabric atomics, correctness-preserving
        float* sp = sums + (size_t)row * 10;
        #pragma unroll
        for (int t = 0; t < 9; t++) atomicAdd(&sp[t], F[t]);
        atomicAdd(&sp[9], 1.0f);
      }
    }
    __syncthreads();
    // ---- flush detect: one thread per bucket queues full 16-record chunks (from the top)
    if (tid < KB){
      int c = min(s_cnt[tid], CAPL);
      int nf = c >> 4;
      int rem = c & (FLC - 1);
      if (nf > 0){
        int off = s_gof[tid];
        s_gof[tid] = off + nf * FLC;
        for (int k = 0; k < nf; k++){
          int q = atomicAdd(&s_nq, 1);
          s_qb[q] = (tid << 8) | (rem + k * FLC);
          int doff = off + k * FLC;
          s_qd[q] = (doff + FLC <= CAPG) ? doff : -1;
        }
        s_cnt[tid] = rem;
      }
    }
    __syncthreads();
    // ---- cooperative copy: 48 fx4 per chunk, fully coalesced 768B-aligned writes
    const int nq = s_nq;
    for (int i = tid; i < nq * (FLC * RSZ / 4); i += RTH){
      int q  = i / (FLC * RSZ / 4);
      int d4 = i - q * (FLC * RSZ / 4);
      int bb = s_qb[q] >> 8, ss = s_qb[q] & 255;
      int doff = s_qd[q];
      if (doff >= 0){
        fx4 v = *(const fx4*)(s_buf + (bb * CAPL + ss) * RSZ + d4 * 4);
        *(fx4*)(recs + ((size_t)(bb * NABLK + ablk) * CAPG + doff) * RSZ + d4 * 4) = v;
      } else {
        // stream-region overflow (rare): per-dword fabric atomics
        #pragma unroll
        for (int w = 0; w < 4; w++){
          int d = d4 * 4 + w;
          int rec = d / RSZ, dd = d - rec * RSZ;
          if (dd >= 1 && dd <= 10){
            float lf = s_buf[(bb * CAPL + ss + rec) * RSZ];
            int lc; __builtin_memcpy(&lc, &lf, 4);
            float* sp = sums + (size_t)((bb << 10) + lc) * 10;
            if (dd <= 9) atomicAdd(&sp[dd - 1], s_buf[(bb * CAPL + ss) * RSZ + d]);
            else         atomicAdd(&sp[9], 1.0f);
          }
        }
      }
    }
    __syncthreads();
    if (tid == 0) s_nq = 0;   // safe: next read is after the classify barrier
  }

  // ---- drain leftovers (<16 per bucket) + write counts
  for (int i = tid; i < KB * (FLC * RSZ); i += RTH){
    int b = i / (FLC * RSZ);
    int d = i - b * (FLC * RSZ);
    int rec = d / RSZ, dd = d - rec * RSZ;
    if (rec < s_cnt[b]){
      int off = s_gof[b] + rec;
      float v = s_buf[(b * CAPL + rec) * RSZ + dd];
      if (off < CAPG){
        recs[((size_t)(b * NABLK + ablk) * CAPG + off) * RSZ + dd] = v;
      } else if (dd >= 1 && dd <= 10){
        float lf = s_buf[(b * CAPL + rec) * RSZ];
        int lc; __builtin_memcpy(&lc, &lf, 4);
        float* sp = sums + (size_t)((b << 10) + lc) * 10;
        if (dd <= 9) atomicAdd(&sp[dd - 1], v);
        else         atomicAdd(&sp[9], 1.0f);
      }
    }
  }
  if (tid < KB)
    counts[tid * NABLK + ablk] = min(s_gof[tid] + s_cnt[tid], CAPG);
}

// ---------------- Phase B: per (bucket, sp) sub-block, sequential record reads, LDS accumulate
#define APS2 (NABLK / SPLITN)   // 32 phase-A blocks per sub-block

__global__ __launch_bounds__(256) void k_accum(const float* __restrict__ recs,
                                               const int* __restrict__ counts,
                                               float* __restrict__ part, int CAPG)
{
  __shared__ int   s_pref[APS2 + 1];
  __shared__ float s_acc[1024 * 11];      // stride 11: gcd(11,32)=1
  const int bucket = blockIdx.x / SPLITN;
  const int sp     = blockIdx.x - bucket * SPLITN;
  const int tid    = threadIdx.x;

  if (tid < APS2) s_pref[tid + 1] = counts[bucket * NABLK + sp * APS2 + tid];
  if (tid == 0) s_pref[0] = 0;
  for (int i = tid; i < 1024 * 11; i += 256) s_acc[i] = 0.f;
  __syncthreads();
  #pragma unroll
  for (int off = 1; off < APS2; off <<= 1){
    int v = 0;
    if (tid < APS2 && tid + 1 > off) v = s_pref[tid + 1 - off];
    __syncthreads();
    if (tid < APS2) s_pref[tid + 1] += v;
    __syncthreads();
  }
  const int total = s_pref[APS2];

  for (int base = 0; base < total; base += 1024){
    int got[4]; size_t ra[4];
    #pragma unroll
    for (int u = 0; u < 4; u++){
      got[u] = 0; ra[u] = 0;
      int idx = base + u * 256 + tid;
      if (idx < total){
        int lo = 0, hi = APS2;
        while (hi - lo > 1){ int mid = (lo + hi) >> 1; if (s_pref[mid] <= idx) lo = mid; else hi = mid; }
        int slot = idx - s_pref[lo];
        int ablk = sp * APS2 + lo;
        ra[u] = ((size_t)(bucket * NABLK + ablk) * CAPG + slot) * RSZ;
        got[u] = 1;
      }
    }
    fx4 r0[4], r1[4], r2[4];
    #pragma unroll
    for (int u = 0; u < 4; u++){
      if (got[u]){
        const fx4* rp = (const fx4*)(recs + ra[u]);   // 48B-aligned sequential
        r0[u] = rp[0]; r1[u] = rp[1]; r2[u] = rp[2];
      }
    }
    #pragma unroll
    for (int u = 0; u < 4; u++){
      if (got[u]){
        int lc; float lf = r0[u][0]; __builtin_memcpy(&lc, &lf, 4);
        float* ap = s_acc + lc * 11;
        atomicAdd(&ap[0], r0[u][1]); atomicAdd(&ap[1], r0[u][2]); atomicAdd(&ap[2], r0[u][3]);
        atomicAdd(&ap[3], r1[u][0]); atomicAdd(&ap[4], r1[u][1]); atomicAdd(&ap[5], r1[u][2]);
        atomicAdd(&ap[6], r1[u][3]); atomicAdd(&ap[7], r2[u][0]); atomicAdd(&ap[8], r2[u][1]);
        atomicAdd(&ap[9], 1.0f);
      }
    }
  }
  __syncthreads();
  float* pb = part + (size_t)(bucket * SPLITN + sp) * 10240;
  for (int i = tid; i < 10240; i += 256)
    pb[i] = s_acc[(i / 10) * 11 + (i % 10)];
}

// ---------------- Kernel C: node main pass (vh, vdf, vnorm, Fsum->sh, MFMA s, silu, gate, vrep)
#define NPB 64
#define MS  168   // padded row stride (elements); 168*2B/4 = 84 ≡ 20 mod 32 -> <=2-way LDS conflicts
#define WGS 136   // sm_wg row stride (shorts): 272B, 16B-aligned, 68 dw ≡ 4 mod 32 -> <=2-way

__global__ __launch_bounds__(256) void k_node(
    const float* __restrict__ scalar, const float* __restrict__ vec,
    const float* __restrict__ sums,   const float* __restrict__ part,
    const float* __restrict__ wdown, const float* __restrict__ wdf,
    const ushort_t* __restrict__ wpk, const float* __restrict__ bso,
    const float* __restrict__ wup,   const float* __restrict__ wg,
    const float* __restrict__ bg,
    float* __restrict__ out0, float* __restrict__ out1, int N)
{
  __shared__ __align__(16) ushort_t sm_merged[NPB * MS];  // phases 0-1: first 12288B hold vec f32
  __shared__ __align__(16) ushort_t sm_vh[NPB * 48];
  __shared__ __align__(16) ushort_t sm_wg[16 * WGS];
  __shared__ float  sm_sh[NPB * 10];     // Fsum[9] + cnt per node
  __shared__ float  sm_vdf[NPB * 9];     // vdf[d*3+c] per node
  __shared__ float  sm_wup[256];
  __shared__ float  sm_wd[256];          // transposed: sm_wd[k*16+h] = wdown[h*16+k]
  __shared__ float  sm_wdf[48];
  __shared__ float  sm_bso[128];
  __shared__ float  sm_bg[16];

  const int tid = threadIdx.x;
  const int n0  = blockIdx.x * NPB;

  // ---- phase 0: stage vec (as f32 into sm_merged), wd/wdf, reduce partial Fsum tables
  {
    int nv = N - n0; if (nv > NPB) nv = NPB;
    const int valid = nv * 48;
    fx4* scratch = (fx4*)sm_merged;
    for (int idx = tid; idx < NPB*48/4; idx += 256){
      fx4 val = {0.f, 0.f, 0.f, 0.f};
      if (idx*4 < valid) val = *(const fx4*)(vec + (size_t)n0*48 + idx*4);
      scratch[idx] = val;
    }
  }
  sm_wd[tid] = wdown[(tid & 15)*16 + (tid >> 4)];   // transpose on load
  if (tid < 48) sm_wdf[tid] = wdf[tid];
  for (int idx = tid; idx < NPB*10; idx += 256){
    int ni = idx / 10, sl = idx - ni*10;
    int g = n0 + ni;
    float acc = 0.f;
    if (g < N){
      acc = sums[(size_t)g*10 + sl];           // rare overflow-fallback adds (usually 0)
      if (part){
        int bucket = g >> 10, loc = g & 1023;
        const float* pb = part + (size_t)bucket * SPLITN * 10240 + loc * 10 + sl;
        #pragma unroll
        for (int sp = 0; sp < SPLITN; sp++) acc += pb[(size_t)sp * 10240];
      }
    }
    sm_sh[idx] = acc;
  }
  __syncthreads();

  // ---- phase 1: vh (1024 items (ni,h), weight reads broadcast) + vdf (192 items)
  #pragma unroll
  for (int it = 0; it < 4; it++){
    int idx = tid + it*256;
    int ni = idx >> 4, h = idx & 15;
    const float* sv = (const float*)sm_merged + ni*48;
    float a0 = 0.f, a1 = 0.f, a2 = 0.f;
    #pragma unroll
    for (int k = 0; k < 16; k++){
      float w = sm_wd[k*16 + h];
      a0 += sv[k*3+0]*w; a1 += sv[k*3+1]*w; a2 += sv[k*3+2]*w;
    }
    sm_vh[ni*48 +  0 + h] = f2bf(a0);
    sm_vh[ni*48 + 16 + h] = f2bf(a1);
    sm_vh[ni*48 + 32 + h] = f2bf(a2);
  }
  if (tid < NPB*3){
    const int ni = tid / 3, d = tid - ni*3;
    const float* sv = (const float*)sm_merged + ni*48;
    float c0 = 0.f, c1 = 0.f, c2 = 0.f;
    #pragma unroll
    for (int k = 0; k < 16; k++){
      float v = sv[k*3 + d];
      c0 += v * sm_wdf[ 0 + k];
      c1 += v * sm_wdf[16 + k];
      c2 += v * sm_wdf[32 + k];
    }
    sm_vdf[ni*9 + d*3 + 0] = c0;
    sm_vdf[ni*9 + d*3 + 1] = c1;
    sm_vdf[ni*9 + d*3 + 2] = c2;
  }
  __syncthreads();

  // ---- phase 2: assemble merged row (scalar | vnorm | sh | pad), stage small tensors
  for (int idx = tid; idx < NPB*32; idx += 256){
    int ni = idx >> 5, c4 = (idx & 31) * 4;
    int g = n0 + ni;
    if (g < N){
      fx4 x = *(const fx4*)(scalar + (size_t)g*128 + c4);
      bfx4 b; b[0]=f2bf(x[0]); b[1]=f2bf(x[1]); b[2]=f2bf(x[2]); b[3]=f2bf(x[3]);
      *(bfx4*)(sm_merged + ni*MS + c4) = b;
    } else {
      bfx4 b = {0,0,0,0};
      *(bfx4*)(sm_merged + ni*MS + c4) = b;
    }
  }
  #pragma unroll
  for (int it = 0; it < 4; it++){
    int idx = tid + it*256;
    int ni = idx >> 4, h = idx & 15;
    float x0 = bf2f(sm_vh[ni*48 +  0 + h]);
    float x1 = bf2f(sm_vh[ni*48 + 16 + h]);
    float x2 = bf2f(sm_vh[ni*48 + 32 + h]);
    sm_merged[ni*MS + 128 + h] = f2bf(sqrtf(x0*x0 + x1*x1 + x2*x2 + 1e-8f));
  }
  // sh[c*3+i] = (Fsum[i][:] . vdf[:][c]) / max(cnt,1)   (factorized rotation, per node)
  for (int idx = tid; idx < NPB*9; idx += 256){
    int ni = idx / 9, t = idx - ni*9;
    int c = t / 3, i3 = (t - c*3) * 3;
    float cnt = sm_sh[ni*10 + 9];
    float inv = 1.0f / fmaxf(cnt, 1.0f);
    const float* Fs = sm_sh + ni*10;
    const float* vd = sm_vdf + ni*9;
    float val = Fs[i3+0]*vd[0*3+c] + Fs[i3+1]*vd[1*3+c] + Fs[i3+2]*vd[2*3+c];
    sm_merged[ni*MS + 144 + t] = f2bf(val * inv);
  }
  for (int idx = tid; idx < NPB*7; idx += 256){
    int ni = idx / 7, t = idx - ni*7;
    sm_merged[ni*MS + 153 + t] = 0;            // zero MFMA pad cols 153..159
  }
  for (int idx = tid; idx < 2048; idx += 256)
    sm_wg[(idx >> 7)*WGS + (idx & 127)] = f2bf(wg[idx]);
  sm_wup[tid] = wup[tid];
  if (tid < 128) sm_bso[tid] = bso[tid];
  if (tid < 16) sm_bg[tid] = bg[tid];
  __syncthreads();

  // ---- phase 3: MFMA (B-fragments streamed from prepacked global, L2-resident)
  const int lane = tid & 63;
  const int wv   = tid >> 6;
  const int mrow = lane & 15;
  const int quad = lane >> 4;
  sfx8 afr[5];
  {
    const ushort_t* ab = sm_merged + (wv*16 + mrow)*MS + quad*8;
    #pragma unroll
    for (int ks = 0; ks < 5; ks++) afr[ks] = *(const sfx8*)(ab + ks*32);
  }
  const ushort_t* wb = wpk + lane*8;
  #pragma unroll
  for (int nt = 0; nt < 8; nt++){
    fx4 acc = {0.f, 0.f, 0.f, 0.f};
    #pragma unroll
    for (int ks = 0; ks < 5; ks++){
      sfx8 bfr = *(const sfx8*)(wb + (size_t)(nt*5 + ks)*64*8);
      acc = __builtin_amdgcn_mfma_f32_16x16x32_bf16(afr[ks], bfr, acc, 0, 0, 0);
    }
    const int o = nt*16 + mrow;
    const float bso_v = sm_bso[o];
    #pragma unroll
    for (int r = 0; r < 4; r++){
      int m = quad*4 + r;
      int g = n0 + wv*16 + m;
      float s = acc[r] + bso_v;
      float sact = s / (1.f + __expf(-s));
      if (g < N) out0[(size_t)g*128 + o] = sact;
      sm_merged[(wv*16 + m)*MS + o] = f2bf(sact);
    }
  }
  __syncthreads();

  // ---- phase 4: gate + vrep
  for (int it = 0; it < 4; it++){
    int widx = tid + it*256;
    int ni = widx >> 4, o16 = widx & 15;
    int g = n0 + ni;
    float acc = sm_bg[o16];
    #pragma unroll
    for (int j8 = 0; j8 < 16; j8++){
      bfx8 svv = *(const bfx8*)(sm_merged + ni*MS + j8*8);
      bfx8 wv8 = *(const bfx8*)(sm_wg + o16*WGS + j8*8);
      #pragma unroll
      for (int t = 0; t < 8; t++) acc += bf2f(svv[t]) * bf2f(wv8[t]);
    }
    float sig = 1.f / (1.f + __expf(-acc));
    #pragma unroll
    for (int d = 0; d < 3; d++){
      float r = 0.f;
      #pragma unroll
      for (int h = 0; h < 16; h++)
        r += bf2f(sm_vh[ni*48 + d*16 + h]) * sm_wup[o16*16 + h];
      if (g < N) out1[((size_t)g*16 + o16)*3 + d] = r * sig;
    }
  }
}

extern "C" void kernel_launch(void* const* d_in, const int* in_sizes, int n_in,
                              void* d_out, int out_size, void* d_ws, size_t ws_size,
                              hipStream_t stream)
{
  const float* scalar = (const float*)d_in[0];
  const float* vec    = (const float*)d_in[1];
  const int*   ei     = (const int*)d_in[2];
  const float* frames = (const float*)d_in[3];
  const float* wdown  = (const float*)d_in[4];
  const float* wdf    = (const float*)d_in[5];
  const float* wso    = (const float*)d_in[6];
  const float* bso    = (const float*)d_in[7];
  const float* wup    = (const float*)d_in[8];
  const float* wg     = (const float*)d_in[9];
  const float* bg     = (const float*)d_in[10];

  const int N = in_sizes[0] / 128;
  const int E = in_sizes[2] / 2;
  const int KB  = (N + 1023) >> 10;                // buckets of 1024 nodes
  const int EPB = (E + NABLK - 1) / NABLK;         // edges per phase-A block

  // per-(bucket,ablock) stream capacity: mean + 3.5 sigma + slack, 16-aligned
  float lam = (float)EPB / (float)KB;
  int capg = (int)(lam + 3.5f * sqrtf(lam) + 17.0f);
  capg = (capg + 15) & ~15;

  char* wp = (char*)d_ws;
  float*    sums  = (float*)wp;                    wp += (size_t)N * 10 * sizeof(float);
  ushort_t* wpk   = (ushort_t*)wp;                 wp += (size_t)8*5*64*8 * sizeof(ushort_t);
  int*      counts= (int*)wp;                      wp += (size_t)KB * NABLK * sizeof(int);
  float*    recs  = (float*)wp;                    wp += (size_t)KB * NABLK * capg * RSZ * sizeof(float);
  float*    part  = (float*)wp;                    wp += (size_t)KB * SPLITN * 10240 * sizeof(float);
  const size_t ws_needed = (size_t)(wp - (char*)d_ws);

  float* out0 = (float*)d_out;                     // silu(s): N x 128 f32
  float* out1 = out0 + (size_t)N * 128;            // vrep:    N x 16 x 3 f32

  const bool binned = (ws_size >= ws_needed) && (KB <= KBMAX) && (E < (1 << 25));

  (void)hipMemsetAsync(sums, 0, (size_t)N * 10 * sizeof(float), stream);
  k_pack<<<(8*5*64*8 + 255)/256, 256, 0, stream>>>(wso, wpk);
  if (binned){
    k_part<<<NABLK, RTH, 0, stream>>>(ei, frames, recs, counts, sums, E, EPB, KB, capg);
    k_accum<<<KB * SPLITN, 256, 0, stream>>>(recs, counts, part, capg);
  } else {
    k_edge<<<(E + 255) / 256, 256, 0, stream>>>(ei, frames, sums, E);
  }
  k_node<<<(N + NPB - 1) / NPB, 256, 0, stream>>>(scalar, vec, sums, binned ? part : nullptr,
                                                  wdown, wdf, wpk, bso, wup, wg, bg, out0, out1, N);
}